// Round 5
// baseline (162.814 us; speedup 1.0000x reference)
//
#include <hip/hip_runtime.h>

typedef _Float16 f16;
typedef __attribute__((ext_vector_type(8))) _Float16 f16x8;
typedef __attribute__((ext_vector_type(4))) float f32x4;

#define ND 256
#define OD 256

// ws layout: rs int[ng+1] | pad to 256B | W2 f16[32][256][8] (128 KB)

__global__ void k_rowstarts(const int* __restrict__ b32, int N, int ng, int* __restrict__ rs) {
    __shared__ int s_is64;
    if (threadIdx.x == 0) {
        // Sniff dtype: int64 batch has zero high words.
        int m = (N / 2) & ~1;
        bool oz = true;
        for (int j = 0; j < 8; ++j) oz &= (b32[m + 2*j + 1] == 0);
        s_is64 = oz ? 1 : 0;
    }
    __syncthreads();
    const bool is64 = (s_is64 != 0);
    int g = blockIdx.x * blockDim.x + threadIdx.x;
    if (g > ng) return;
    int lo = 0, hi = N;
    while (lo < hi) {
        int mid = (lo + hi) >> 1;
        int v = is64 ? b32[2*mid] : b32[mid];
        if (v < g) lo = mid + 1; else hi = mid;
    }
    rs[g] = lo;
}

// Repack value_w [k][j] -> W2 [k/8][j][k%8] as f16 (B-frag = 16 contiguous bytes).
__global__ void k_wpack(const float* __restrict__ W, f16* __restrict__ W2) {
    const int kb = blockIdx.x;      // 0..31
    const int j  = threadIdx.x;     // 0..255
    f16x8 v;
    #pragma unroll
    for (int e = 0; e < 8; ++e)
        v[e] = (f16)W[(size_t)(kb * 8 + e) * OD + j];
    *(f16x8*)(W2 + (size_t)kb * 2048 + j * 8) = v;
}

// Issue one 16-row chunk of x into a named register bank (plain arrays,
// compile-time indices after unroll: stays in VGPRs; no address capture).
#define ISSUE_CHUNK(RA, RB, ROW)                                             \
    {                                                                        \
        const int r_ = (ROW);                                                \
        const bool v_ = r_ < segN;                                           \
        const float* xp_ = x + (size_t)(seg0 + r_) * ND + h * 8;             \
        _Pragma("unroll")                                                    \
        for (int ks = 0; ks < 8; ++ks) {                                     \
            if (v_) {                                                        \
                RA[ks] = *(const float4*)(xp_ + ks * 32);                    \
                RB[ks] = *(const float4*)(xp_ + ks * 32 + 4);                \
            } else {                                                         \
                RA[ks] = f4z; RB[ks] = f4z;                                  \
            }                                                                \
        }                                                                    \
    }

// Consume a bank: gate partial dot (f32) + convert to f16 A-fragments.
#define CONSUME_CHUNK(RA, RB, AV, GP)                                        \
    {                                                                        \
        float g1_ = 0.f, g2_ = 0.f;                                          \
        _Pragma("unroll")                                                    \
        for (int ks = 0; ks < 8; ++ks) {                                     \
            const float4 a = RA[ks], b = RB[ks];                             \
            const float4 wa = *(const float4*)(gwl + ks * 32 + h * 8);       \
            const float4 wb = *(const float4*)(gwl + ks * 32 + h * 8 + 4);   \
            g1_ += (a.x*wa.x + a.y*wa.y) + (a.z*wa.z + a.w*wa.w);            \
            g2_ += (b.x*wb.x + b.y*wb.y) + (b.z*wb.z + b.w*wb.w);            \
            AV[ks][0] = (f16)a.x; AV[ks][1] = (f16)a.y;                      \
            AV[ks][2] = (f16)a.z; AV[ks][3] = (f16)a.w;                      \
            AV[ks][4] = (f16)b.x; AV[ks][5] = (f16)b.y;                      \
            AV[ks][6] = (f16)b.z; AV[ks][7] = (f16)b.w;                      \
        }                                                                    \
        GP = g1_ + g2_;                                                      \
    }

// One 16-row pipeline step: issue NEXT bank, then consume CURRENT bank,
// gate softmax-weight, and the 16-col-slice MFMA+silu accumulation.
// Bank names are static per expansion (rule #20: no runtime indexing).
#define STEP(CA, CB, NA, NB, T)                                              \
    {                                                                        \
        const int row_ = (T) * 16 + rowl;                                    \
        const bool vr_ = row_ < segN;                                        \
        ISSUE_CHUNK(NA, NB, ((T) + 1) * 16 + rowl);                          \
        __builtin_amdgcn_sched_barrier(0);   /* pin prefetch issue above */  \
        __builtin_amdgcn_s_setprio(1);                                       \
        float gp_;                                                           \
        f16x8 av[8];                                                         \
        CONSUME_CHUNK(CA, CB, av, gp_);                                      \
        gp_ += __shfl_xor(gp_, 16, 64);                                      \
        gp_ += __shfl_xor(gp_, 32, 64);                                      \
        const float wv_ = vr_ ? __expf(fminf(gp_ + gb, 60.f)) : 0.f;         \
        if (h == 0 && vr_) attn[seg0 + row_] = wv_;   /* stash exp(g) */     \
        S += (h == 0) ? wv_ : 0.f;                    /* deferred reduce */  \
        const float w0 = __shfl(wv_, h * 4 + 0, 64);                         \
        const float w1 = __shfl(wv_, h * 4 + 1, 64);                         \
        const float w2 = __shfl(wv_, h * 4 + 2, 64);                         \
        const float w3 = __shfl(wv_, h * 4 + 3, 64);                         \
        _Pragma("unroll 2")                                                  \
        for (int cs = 0; cs < 16; ++cs) {                                    \
            f32x4 ac = {0.f, 0.f, 0.f, 0.f};                                 \
            const char* bb = (const char*)Bl + h * 4096                      \
                           + (size_t)(cs * 16 + rowl) * 16;                  \
            _Pragma("unroll")                                                \
            for (int ks = 0; ks < 8; ++ks) {                                 \
                const f16x8 bf = *(const f16x8*)(bb + ks * 16384);           \
                ac = __builtin_amdgcn_mfma_f32_16x16x32_f16(av[ks], bf, ac, 0, 0, 0); \
            }                                                                \
            const float vbv = vbl[cs * 16 + rowl];                           \
            float p0 = ac[0] + vbv, p1 = ac[1] + vbv;                        \
            float p2 = ac[2] + vbv, p3 = ac[3] + vbv;                        \
            zs[cs] += w0 * p0 * __builtin_amdgcn_rcpf(1.f + __expf(-p0))     \
                    + w1 * p1 * __builtin_amdgcn_rcpf(1.f + __expf(-p1))     \
                    + w2 * p2 * __builtin_amdgcn_rcpf(1.f + __expf(-p2))     \
                    + w3 * p3 * __builtin_amdgcn_rcpf(1.f + __expf(-p3));    \
        }                                                                    \
        __builtin_amdgcn_s_setprio(0);                                       \
    }

// LDS (128 KB) -> 1 block/CU = 2 waves/SIMD. min-2-waves/EU pins the
// 256-VGPR budget (peak live ~180: one bank in flight across the cs loop).
__global__ __launch_bounds__(512, 2)
void k_main(const float* __restrict__ x, const int* __restrict__ rs,
            const float* __restrict__ gate_w, const float* __restrict__ gate_b,
            const f16* __restrict__ W2, const float* __restrict__ value_b,
            float* __restrict__ zout, float* __restrict__ attn, int ng) {
    __shared__ __align__(16) f16 Bl[32 * 256 * 8];   // 128 KB, [kb][col][8]
    __shared__ float gwl[ND];
    __shared__ float vbl[OD];

    const int tid = threadIdx.x;    // 0..511
    const int wid = tid >> 6;       // 0..7
    const int lane = tid & 63;
    const int rowl = lane & 15;
    const int h = lane >> 4;

    // one-time: B -> LDS (coalesced linear), gate_w / value_b -> LDS
    #pragma unroll
    for (int i = 0; i < 16; ++i) {
        const int f = i * 512 + tid;
        *(f16x8*)((char*)Bl + (size_t)f * 16) = *(const f16x8*)(W2 + (size_t)f * 8);
    }
    if (tid < ND) gwl[tid] = gate_w[tid];
    else if (tid < ND + OD) vbl[tid - ND] = value_b[tid - ND];
    __syncthreads();   // ONLY block barrier

    const float gb = gate_b[0];
    const float4 f4z = make_float4(0.f, 0.f, 0.f, 0.f);

    #pragma unroll 1
    for (int gq = 0; gq < 2; ++gq) {
        const int g = blockIdx.x * 16 + gq * 8 + wid;   // wave-uniform
        if (g >= ng) continue;
        const int seg0 = rs[g], seg1 = rs[g + 1];
        const int segN = seg1 - seg0;

        float S = 0.f;                                  // per-lane partial (h==0 masked)
        float zs[16];
        #pragma unroll
        for (int cs = 0; cs < 16; ++cs) zs[cs] = 0.f;

        const int nt = (segN + 15) >> 4;   // 16-row tiles

        // 2-deep pipeline over two static banks: while tile t computes,
        // tile t+1's 16 KB is in flight -> the VMEM queue never drains.
        float4 ra[8], rb[8];     // bank A
        float4 rc[8], rd[8];     // bank B

        ISSUE_CHUNK(ra, rb, rowl);          // prologue: tile 0 -> bank A

        #pragma unroll 1
        for (int t = 0; t < nt; t += 2) {
            STEP(ra, rb, rc, rd, t);                    // consume A, issue B
            if (t + 1 < nt) STEP(rc, rd, ra, rb, t + 1); // consume B, issue A
        }

        // graph end: single S butterfly (h!=0 lanes hold 0 partials)
        #pragma unroll
        for (int off = 32; off >= 1; off >>= 1) S += __shfl_xor(S, off, 64);

        const float inv = __builtin_amdgcn_rcpf(S + 1e-8f);
        #pragma unroll
        for (int cs = 0; cs < 16; ++cs) {
            float v = zs[cs];
            v += __shfl_xor(v, 16, 64);
            v += __shfl_xor(v, 32, 64);
            if (lane < 16) zout[(size_t)g * OD + cs * 16 + lane] = v * inv;
        }
        asm volatile("s_waitcnt vmcnt(0)" ::: "memory");   // exp(g) stores visible
        for (int i = seg0 + lane; i < seg1; i += 64)
            attn[i] = attn[i] * inv;                        // pure scale
    }
}

extern "C" void kernel_launch(void* const* d_in, const int* in_sizes, int n_in,
                              void* d_out, int out_size, void* d_ws, size_t ws_size,
                              hipStream_t stream) {
    const float* x       = (const float*)d_in[0];
    const int*   batch   = (const int*)d_in[1];
    const float* gate_w  = (const float*)d_in[3];
    const float* gate_b  = (const float*)d_in[4];
    const float* value_w = (const float*)d_in[5];
    const float* value_b = (const float*)d_in[6];

    const int N  = in_sizes[1];
    const int ng = (out_size - N) / OD;

    int* rs = (int*)d_ws;
    f16* W2 = (f16*)(((uintptr_t)(rs + ng + 1) + 255) & ~(uintptr_t)255);

    k_rowstarts<<<(ng + 1 + 255) / 256, 256, 0, stream>>>(batch, N, ng, rs);
    k_wpack<<<32, 256, 0, stream>>>(value_w, W2);

    float* zout = (float*)d_out;
    float* attn = zout + (size_t)ng * OD;

    k_main<<<(ng + 15) / 16, 512, 0, stream>>>(x, rs, gate_w, gate_b, W2, value_b,
                                               zout, attn, ng);
}